// Round 7
// baseline (494.861 us; speedup 1.0000x reference)
//
#include <hip/hip_runtime.h>

// RelationAwareAttention: BS=4,H=8,L=1024,D=64,P=513, fp32 in/out.
// out = [attn_sum (B,H,L,D) | p_attn (B,H,L,L)] flat fp32.
//
// R7: prep1 (job-split): SR score_r table; Qh/Ql,Kh/Kl bf16 planes; Vt; Rt.
//     prep2: GP packed gather table (bf16 score | u16 pm), mask folded.
//     raa_qks (XCD-swizzled): QK^T + softmax + fp32 p_attn, no big LDS.
//     raa_pv  (XCD-swizzled, 1024 thr, 71KB LDS): single-pass stage of P+GP ->
//       registers; bf16 P into swizzled LDS; bucket scatter from regs (LDS
//       atomics); PV + bucket GEMMs with A-frags from LDS, B from L2 Vt/Rt.
//     Fallback if ws too small.

#define BSZ 4
#define NH 8
#define LSEQ 1024
#define DH 64
#define NP 513
#define TI 16
#define SRX 548            // LDS bucket row stride (floats): 16B-aligned
#define RTC 544            // Rt padded cols

#define NQE (BSZ*NH*LSEQ*DH)   // 2097152 elems per plane
#define NRT (BSZ*DH*RTC)       // 139264
#define NSR (BSZ*LSEQ*NP)      // 2101248
#define NGPW (2*BSZ*LSEQ*LSEQ) // GP span in ushort units
#define OFF_QH 0
#define OFF_QL (NQE)
#define OFF_KH (2*NQE)
#define OFF_KL (3*NQE)
#define OFF_VT (4*NQE)
#define OFF_RT (5*NQE)
#define OFF_SR (5*NQE + NRT)
#define OFF_GP (5*NQE + NRT + NSR)
#define WS_NEED ((size_t)(OFF_GP + NGPW) * 2)

#define NB_SR 512
#define NB_QK 4096
#define NB_VT 512
#define NB_RT 544
#define NB_P1 (NB_SR + NB_QK + NB_VT + NB_RT)

typedef __attribute__((ext_vector_type(8))) short bf16x8;
typedef __attribute__((ext_vector_type(4))) float f32x4;
typedef __attribute__((ext_vector_type(4))) ushort u16x4;
typedef __attribute__((ext_vector_type(4))) uint u32x4;

__device__ __forceinline__ ushort f2bf(float x) {
    uint u = __float_as_uint(x);
    u += 0x7FFFu + ((u >> 16) & 1u);
    return (ushort)(u >> 16);
}
__device__ __forceinline__ float bf2f(ushort h) {
    return __uint_as_float(((uint)h) << 16);
}

// ---------------- prep1: SR | qk planes | vt | rt (SR dispatched first) ------

__global__ __launch_bounds__(256) void prep1(
    const float* __restrict__ Q, const float* __restrict__ K,
    const float* __restrict__ V, const float* __restrict__ REL,
    ushort* __restrict__ ws)
{
    __shared__ float sT[64 * 65];
    const int bid = blockIdx.x;
    const int tid = threadIdx.x;

    if (bid < NB_SR) {
        // ---- job SR: score_r = Q(head0) . REL^T, bf16 table (once per b) ----
        const int b = bid >> 7;
        const int r = bid & 127;
        const int it = r >> 1, half = r & 1;
        const int i0 = it * TI;
        const int w = tid >> 6, l = tid & 63, lg = l >> 4, lm = l & 15;

        const float* Qb0 = Q + ((size_t)b * NH) * LSEQ * DH;
        const float* RELb = REL + (size_t)b * NP * DH;
        ushort* SRb = ws + OFF_SR + (size_t)b * LSEQ * NP;

        bf16x8 qh[2], ql[2];
        #pragma unroll
        for (int ks = 0; ks < 2; ++ks) {
            const float* qs = Qb0 + (size_t)(i0 + lm) * DH + ks * 32 + lg * 8;
            float4 v0 = *(const float4*)(qs);
            float4 v1 = *(const float4*)(qs + 4);
            float xs[8] = {v0.x, v0.y, v0.z, v0.w, v1.x, v1.y, v1.z, v1.w};
            #pragma unroll
            for (int e = 0; e < 8; ++e) {
                ushort hi = f2bf(xs[e]);
                qh[ks][e] = (short)hi;
                ql[ks][e] = (short)f2bf(xs[e] - bf2f(hi));
            }
        }

        int ctb = half ? 33 : 16;
        for (int ct = half * 16 + w; ct < ctb; ct += 4) {
            int p0 = ct * 16;
            int prow = p0 + lm; if (prow > 512) prow = 512;
            f32x4 a0 = {0.f, 0.f, 0.f, 0.f};
            #pragma unroll
            for (int ks = 0; ks < 2; ++ks) {
                const float* bsrc = RELb + (size_t)prow * DH + ks * 32 + lg * 8;
                float4 v0 = *(const float4*)(bsrc);
                float4 v1 = *(const float4*)(bsrc + 4);
                float xs[8] = {v0.x, v0.y, v0.z, v0.w, v1.x, v1.y, v1.z, v1.w};
                bf16x8 bh8, bl8;
                #pragma unroll
                for (int e = 0; e < 8; ++e) {
                    ushort hi = f2bf(xs[e]);
                    bh8[e] = (short)hi;
                    bl8[e] = (short)f2bf(xs[e] - bf2f(hi));
                }
                a0 = __builtin_amdgcn_mfma_f32_16x16x32_bf16(qh[ks], bh8, a0, 0, 0, 0);
                a0 = __builtin_amdgcn_mfma_f32_16x16x32_bf16(ql[ks], bh8, a0, 0, 0, 0);
                a0 = __builtin_amdgcn_mfma_f32_16x16x32_bf16(qh[ks], bl8, a0, 0, 0, 0);
            }
            if (p0 + lm < NP) {
                #pragma unroll
                for (int e = 0; e < 4; ++e)
                    SRb[(size_t)(i0 + 4 * lg + e) * NP + p0 + lm] = f2bf(a0[e]);
            }
        }
    } else if (bid < NB_SR + NB_QK) {
        // ---- job QK: Q/K -> bf16 hi/lo planes ----
        const int n4 = NQE / 4;
        int i = (bid - NB_SR) * 256 + tid;
        int isK = i >= n4;
        int base = i - isK * n4;
        float4 v = ((const float4*)(isK ? K : Q))[base];
        float xs[4] = {v.x, v.y, v.z, v.w};
        u16x4 hh, ll;
        #pragma unroll
        for (int e = 0; e < 4; ++e) {
            ushort hi = f2bf(xs[e]);
            hh[e] = hi;
            ll[e] = f2bf(xs[e] - bf2f(hi));
        }
        *(u16x4*)(ws + (isK ? OFF_KH : OFF_QH) + (size_t)base * 4) = hh;
        *(u16x4*)(ws + (isK ? OFF_KL : OFF_QL) + (size_t)base * 4) = ll;
    } else if (bid < NB_SR + NB_QK + NB_VT) {
        // ---- job VT: V transpose (LDS tile) ----
        const int vb = bid - (NB_SR + NB_QK);
        const int bh = vb >> 4;
        const int j0 = (vb & 15) * 64;
        const float* Vb = V + ((size_t)bh << 16);
        for (int i = tid; i < 1024; i += 256) {
            int jr = i >> 4, c4 = i & 15;
            float4 vv = *(const float4*)(Vb + (size_t)(j0 + jr) * DH + c4 * 4);
            float* dst = &sT[jr * 65 + c4 * 4];
            dst[0] = vv.x; dst[1] = vv.y; dst[2] = vv.z; dst[3] = vv.w;
        }
        __syncthreads();
        const int d = tid >> 2, jseg = tid & 3;
        ushort* dst = ws + OFF_VT + ((size_t)bh << 16) + (size_t)d * LSEQ + j0 + jseg * 16;
        #pragma unroll
        for (int g = 0; g < 4; ++g) {
            u16x4 o;
            #pragma unroll
            for (int e = 0; e < 4; ++e)
                o[e] = f2bf(sT[(jseg * 16 + g * 4 + e) * 65 + d]);
            *(u16x4*)(dst + g * 4) = o;
        }
    } else {
        // ---- job RT: REL transpose (padded) ----
        int i = (bid - (NB_SR + NB_QK + NB_VT)) * 256 + tid;
        int b = i / (DH * RTC);
        int r = i - b * (DH * RTC);
        int d = r / RTC;
        int p = r - d * RTC;
        float x = (p < NP) ? REL[((size_t)b * NP + p) * DH + d] : 0.f;
        ws[OFF_RT + i] = f2bf(x);
    }
}

// ---------------- prep2: GP = packed (bf16 gathered score_r | u16 pm) --------

__global__ __launch_bounds__(256) void prep2(
    const int* __restrict__ PM, const int* __restrict__ MASK,
    ushort* __restrict__ ws)
{
    __shared__ ushort sSR[4 * 520];
    const int tid = threadIdx.x;
    const int bid = blockIdx.x;
    const int b = bid >> 8;
    const int row0 = (bid & 255) * 4;

    const ushort* SRb = ws + OFF_SR + (size_t)b * LSEQ * NP;
    uint* GPb = (uint*)(ws + OFF_GP) + (size_t)b * LSEQ * LSEQ;
    const int* PMb = PM + (size_t)b * LSEQ * LSEQ;
    const int* MKb = MASK + (size_t)b * LSEQ * LSEQ;

    for (int i = tid; i < 4 * 520; i += 256) {
        int row = i / 520, col = i - row * 520;
        if (col < NP) sSR[row * 520 + col] = SRb[(size_t)(row0 + row) * NP + col];
    }
    __syncthreads();

    #pragma unroll
    for (int r = 0; r < 4; ++r) {
        int idx4 = r * 256 + tid;
        int row = idx4 >> 8;
        int c0 = (idx4 & 255) * 4;
        size_t off = (size_t)(row0 + row) * LSEQ + c0;
        int4 pm4 = *(const int4*)(PMb + off);
        int4 mk4 = *(const int4*)(MKb + off);
        const ushort* srow = &sSR[row * 520];
        u32x4 o;
        o[0] = ((uint)(mk4.x ? srow[pm4.x] : 0xFF62u) << 16) | (uint)pm4.x;
        o[1] = ((uint)(mk4.y ? srow[pm4.y] : 0xFF62u) << 16) | (uint)pm4.y;
        o[2] = ((uint)(mk4.z ? srow[pm4.z] : 0xFF62u) << 16) | (uint)pm4.z;
        o[3] = ((uint)(mk4.w ? srow[pm4.w] : 0xFF62u) << 16) | (uint)pm4.w;
        *(u32x4*)(GPb + off) = o;
    }
}

// ---------------- kernel A: QK^T + softmax + fp32 p_attn ----------------

__global__ __launch_bounds__(512, 4) void raa_qks(
    const ushort* __restrict__ ws, float* __restrict__ OUT_P)
{
    __shared__ float sRedM[16 * 9];
    __shared__ float sRedS[16 * 9];

    const int tid = threadIdx.x;
    const int w  = tid >> 6;        // 0..7
    const int l  = tid & 63;
    const int lg = l >> 4;
    const int lm = l & 15;

    // XCD-aware decode: xcd = bid&7 owns 4 (b,h) panels x 64 i-tiles
    const int bid = blockIdx.x;
    const int xcd = bid & 7;
    const int idx = bid >> 3;
    const int bh  = (xcd << 2) + (idx >> 6);
    const int it  = idx & 63;
    const int b   = bh >> 3;
    const int i0  = it * TI;

    const ushort* Qh = ws + OFF_QH + (size_t)bh * LSEQ * DH;
    const ushort* Ql = ws + OFF_QL + (size_t)bh * LSEQ * DH;
    const ushort* Kh = ws + OFF_KH + (size_t)bh * LSEQ * DH;
    const ushort* Kl = ws + OFF_KL + (size_t)bh * LSEQ * DH;
    const uint*   GPb = (const uint*)(ws + OFF_GP) + (size_t)b * LSEQ * LSEQ;

    // gathered scores (mask folded), front-loaded
    float gf[32];
    #pragma unroll
    for (int t = 0; t < 8; ++t) {
        #pragma unroll
        for (int e = 0; e < 4; ++e) {
            int col = (8 * w + t) * 16 + lm;
            int row = 4 * lg + e;
            uint g = GPb[(size_t)(i0 + row) * LSEQ + col];
            gf[t * 4 + e] = bf2f((ushort)(g >> 16));
        }
    }

    bf16x8 qhh[2], qhl[2];
    #pragma unroll
    for (int ks = 0; ks < 2; ++ks) {
        size_t ao = (size_t)(i0 + lm) * DH + ks * 32 + lg * 8;
        qhh[ks] = *(const bf16x8*)(Qh + ao);
        qhl[ks] = *(const bf16x8*)(Ql + ao);
    }

    // QK^T: 8 coltiles per wave
    f32x4 acc[8];
    #pragma unroll
    for (int t = 0; t < 8; ++t) {
        size_t bo = (size_t)((8 * w + t) * 16 + lm) * DH + lg * 8;
        bf16x8 kh0 = *(const bf16x8*)(Kh + bo);
        bf16x8 kl0 = *(const bf16x8*)(Kl + bo);
        bf16x8 kh1 = *(const bf16x8*)(Kh + bo + 32);
        bf16x8 kl1 = *(const bf16x8*)(Kl + bo + 32);
        f32x4 a = {0.f, 0.f, 0.f, 0.f};
        a = __builtin_amdgcn_mfma_f32_16x16x32_bf16(qhh[0], kh0, a, 0, 0, 0);
        a = __builtin_amdgcn_mfma_f32_16x16x32_bf16(qhl[0], kh0, a, 0, 0, 0);
        a = __builtin_amdgcn_mfma_f32_16x16x32_bf16(qhh[0], kl0, a, 0, 0, 0);
        a = __builtin_amdgcn_mfma_f32_16x16x32_bf16(qhh[1], kh1, a, 0, 0, 0);
        a = __builtin_amdgcn_mfma_f32_16x16x32_bf16(qhl[1], kh1, a, 0, 0, 0);
        a = __builtin_amdgcn_mfma_f32_16x16x32_bf16(qhh[1], kl1, a, 0, 0, 0);
        acc[t] = a;
    }

    // gather + mask + scale
    #pragma unroll
    for (int i = 0; i < 32; ++i) {
        int t = i >> 2, e = i & 3;
        float g = gf[i];
        acc[t][e] = (g < -1e30f) ? -1e9f : (acc[t][e] + g) * 0.125f;
    }

    // softmax: wave-local (m,s), one barrier, 8-lane combine
    float mw[4], c4v[4];
    #pragma unroll
    for (int e = 0; e < 4; ++e) {
        float m = acc[0][e];
        #pragma unroll
        for (int t = 1; t < 8; ++t) m = fmaxf(m, acc[t][e]);
        #pragma unroll
        for (int o = 8; o >= 1; o >>= 1) m = fmaxf(m, __shfl_xor(m, o));
        mw[e] = m;
        float s = 0.f;
        #pragma unroll
        for (int t = 0; t < 8; ++t) {
            float v = __expf(acc[t][e] - m);
            acc[t][e] = v;
            s += v;
        }
        #pragma unroll
        for (int o = 8; o >= 1; o >>= 1) s += __shfl_xor(s, o);
        if (lm == 0) {
            sRedM[(4 * lg + e) * 9 + w] = m;
            sRedS[(4 * lg + e) * 9 + w] = s;
        }
    }
    __syncthreads();
    #pragma unroll
    for (int e = 0; e < 4; ++e) {
        int row = 4 * lg + e;
        float mv = sRedM[row * 9 + (lm & 7)];
        float sv = sRedS[row * 9 + (lm & 7)];
        float m = mv;
        #pragma unroll
        for (int o = 4; o >= 1; o >>= 1) m = fmaxf(m, __shfl_xor(m, o));
        float sp = sv * __expf(mv - m);
        #pragma unroll
        for (int o = 4; o >= 1; o >>= 1) sp += __shfl_xor(sp, o);
        c4v[e] = __expf(mw[e] - m) / sp;
    }

    // fp32 p_attn store
    const size_t pbase = ((size_t)bh * LSEQ + i0) * LSEQ;
    #pragma unroll
    for (int t = 0; t < 8; ++t) {
        int col = (8 * w + t) * 16 + lm;
        #pragma unroll
        for (int e = 0; e < 4; ++e) {
            int row = 4 * lg + e;
            OUT_P[pbase + (size_t)row * LSEQ + col] = acc[t][e] * c4v[e];
        }
    }
}

// ---------------- kernel B: single-pass stage + scatter + GEMMs ----------------

__global__ __launch_bounds__(1024, 8) void raa_pv(
    const ushort* __restrict__ ws, const float* __restrict__ P_in,
    float* __restrict__ OUT_A)
{
    __shared__ float  X[TI * SRX];       // 35.1 KB buckets
    __shared__ ushort sPb[TI * 1024];    // 32 KB p bf16, chunk-swizzled
    __shared__ float  sAttn[TI * DH];    // 4 KB

    const int tid = threadIdx.x;
    const int w  = tid >> 6;             // 0..15
    const int l  = tid & 63;
    const int lg = l >> 4;
    const int lm = l & 15;

    const int bid = blockIdx.x;
    const int xcd = bid & 7;
    const int idx = bid >> 3;
    const int bh  = (xcd << 2) + (idx >> 6);
    const int it  = idx & 63;
    const int b   = bh >> 3;
    const int i0  = it * TI;

    const ushort* Vt = ws + OFF_VT + (size_t)bh * DH * LSEQ;
    const ushort* Rt = ws + OFF_RT + (size_t)b * DH * RTC;
    const uint*   GPb = (const uint*)(ws + OFF_GP) + (size_t)b * LSEQ * LSEQ;
    const float*  Pb = P_in + ((size_t)bh * LSEQ + i0) * LSEQ;

    // ---- front-load: 4 chunks of (float4 P + u32x4 GP) per thread ----
    float4 p4[4];
    u32x4  g4[4];
    #pragma unroll
    for (int c = 0; c < 4; ++c) {
        int flat = c * 4096 + tid * 4;          // element index in 16x1024 tile
        int r = flat >> 10, cc = flat & 1023;
        p4[c] = *(const float4*)(Pb + (size_t)r * LSEQ + cc);
        g4[c] = *(const u32x4*)(GPb + (size_t)(i0 + r) * LSEQ + cc);
    }

    // ---- zero X + sAttn while loads are in flight ----
    #pragma unroll
    for (int z = 0; z < 9; ++z) {
        int zi = z * 1024 + tid;
        if (zi < TI * SRX) X[zi] = 0.f;
    }
    sAttn[tid] = 0.f;
    __syncthreads();

    // ---- consume: bf16 -> swizzled sPb + bucket scatter from registers ----
    #pragma unroll
    for (int c = 0; c < 4; ++c) {
        int flat = c * 4096 + tid * 4;
        int r = flat >> 10, cc = flat & 1023;
        u16x4 pb;
        pb[0] = f2bf(p4[c].x); pb[1] = f2bf(p4[c].y);
        pb[2] = f2bf(p4[c].z); pb[3] = f2bf(p4[c].w);
        // cols cc..cc+3 lie in one 8-col chunk (cc%4==0): swizzle chunk index
        int ch = cc >> 3;
        int ad = r * 1024 + ((ch ^ (r & 7)) << 3) + (cc & 7);
        *(u16x4*)&sPb[ad] = pb;
        float* xrow = &X[r * SRX];
        atomicAdd(&xrow[g4[c][0] & 0xFFFFu], p4[c].x);
        atomicAdd(&xrow[g4[c][1] & 0xFFFFu], p4[c].y);
        atomicAdd(&xrow[g4[c][2] & 0xFFFFu], p4[c].z);
        atomicAdd(&xrow[g4[c][3] & 0xFFFFu], p4[c].w);
    }
    __syncthreads();

    // ---- GEMMs: waves 0-7 p@V (j-halved, d-quartered); 8-15 buckets@REL ----
    const int d0 = (w & 3) * 16;
    f32x4 pa = {0.f, 0.f, 0.f, 0.f};
    if (w < 8) {
        const int jh = w >> 2;
        #pragma unroll
        for (int ks = 0; ks < 16; ++ks) {
            int j0 = jh * 512 + ks * 32;
            int ch = (j0 >> 3) + lg;
            bf16x8 a = *(const bf16x8*)&sPb[lm * 1024 + ((ch ^ (lm & 7)) << 3)];
            bf16x8 bb = *(const bf16x8*)(Vt + (size_t)(d0 + lm) * LSEQ + j0 + lg * 8);
            pa = __builtin_amdgcn_mfma_f32_16x16x32_bf16(a, bb, pa, 0, 0, 0);
        }
    } else {
        const int ph = (w - 8) >> 2;
        const int nks = ph ? 8 : 9;
        const int pb0 = ph ? 288 : 0;
        #pragma unroll
        for (int ks = 0; ks < 9; ++ks) {
            if (ks >= nks) break;
            int p0 = pb0 + ks * 32;
            const float* xs = &X[lm * SRX + p0 + lg * 8];
            float4 a0 = *(const float4*)(xs);
            float4 a1 = *(const float4*)(xs + 4);
            bf16x8 a;
            a[0] = (short)f2bf(a0.x); a[1] = (short)f2bf(a0.y);
            a[2] = (short)f2bf(a0.z); a[3] = (short)f2bf(a0.w);
            a[4] = (short)f2bf(a1.x); a[5] = (short)f2bf(a1.y);
            a[6] = (short)f2bf(a1.z); a[7] = (short)f2bf(a1.w);
            bf16x8 bb = *(const bf16x8*)(Rt + (size_t)(d0 + lm) * RTC + p0 + lg * 8);
            pa = __builtin_amdgcn_mfma_f32_16x16x32_bf16(a, bb, pa, 0, 0, 0);
        }
    }
    #pragma unroll
    for (int e = 0; e < 4; ++e)
        atomicAdd(&sAttn[(4 * lg + e) * DH + d0 + lm], pa[e]);
    __syncthreads();

    OUT_A[((size_t)bh * LSEQ + i0 + (tid >> 6)) * DH + (tid & 63)] = sAttn[tid];
}

// ---------------- fallback (self-contained, from R2) ----------------

__global__ __launch_bounds__(1024, 4) void raa_fallback(
    const float* __restrict__ Q, const float* __restrict__ K,
    const float* __restrict__ V, const float* __restrict__ REL,
    const int* __restrict__ PM, const int* __restrict__ MASK,
    float* __restrict__ OUT_A, float* __restrict__ OUT_P)
{
    __shared__ ushort sQh[TI * 64];
    __shared__ ushort sQl[TI * 64];
    __shared__ float  sR[TI * NP];
    __shared__ ushort sPb[TI * 1024];
    __shared__ float  sAttn[TI * 64];
    __shared__ float  sRed[16 * 17];
    __shared__ float  sFin[16];

    const int tid = threadIdx.x;
    const int w  = tid >> 6;
    const int l  = tid & 63;
    const int lg = l >> 4;
    const int lm = l & 15;

    const int it = blockIdx.x, h = blockIdx.y, b = blockIdx.z;
    const int i0 = it * TI;

    const float* Qb0  = Q + ((size_t)b * NH + 0) * LSEQ * DH;
    const float* Qbh  = Q + ((size_t)b * NH + h) * LSEQ * DH;
    const float* Kbh  = K + ((size_t)b * NH + h) * LSEQ * DH;
    const float* Vbh  = V + ((size_t)b * NH + h) * LSEQ * DH;
    const float* RELb = REL + (size_t)b * NP * DH;
    const int*   PMb  = PM  + (size_t)b * LSEQ * LSEQ;
    const int*   MKb  = MASK + (size_t)b * LSEQ * LSEQ;

    {
        int row = tid >> 6, kk = tid & 63;
        float x = Qb0[(size_t)(i0 + row) * DH + kk];
        ushort hi = f2bf(x);
        ushort lo = f2bf(x - bf2f(hi));
        int ad = row * 64 + (((kk >> 3) ^ (row & 7)) << 3) + (kk & 7);
        sQh[ad] = hi; sQl[ad] = lo;
        sAttn[tid] = 0.f;
    }
    __syncthreads();

    bf16x8 qh[2], ql[2];
    #pragma unroll
    for (int ks = 0; ks < 2; ++ks) {
        int ch = lg + 4 * ks;
        int ad = lm * 64 + ((ch ^ (lm & 7)) << 3);
        qh[ks] = *(const bf16x8*)&sQh[ad];
        ql[ks] = *(const bf16x8*)&sQl[ad];
    }
    __syncthreads();

    {
        int row = tid >> 6, kk = tid & 63;
        float x = Qbh[(size_t)(i0 + row) * DH + kk];
        ushort hi = f2bf(x);
        ushort lo = f2bf(x - bf2f(hi));
        int ad = row * 64 + (((kk >> 3) ^ (row & 7)) << 3) + (kk & 7);
        sQh[ad] = hi; sQl[ad] = lo;
    }

    for (int ct = w; ct < 33; ct += 16) {
        int p0 = ct * 16;
        int prow = p0 + lm; if (prow > 512) prow = 512;
        const float* bsrc = RELb + (size_t)prow * DH + 8 * lg;
        f32x4 acc = {0.f, 0.f, 0.f, 0.f};
        #pragma unroll
        for (int ks = 0; ks < 2; ++ks) {
            float4 v0 = *(const float4*)(bsrc + ks * 32);
            float4 v1 = *(const float4*)(bsrc + ks * 32 + 4);
            float xs[8] = {v0.x, v0.y, v0.z, v0.w, v1.x, v1.y, v1.z, v1.w};
            bf16x8 bh, bl;
            #pragma unroll
            for (int e = 0; e < 8; ++e) {
                ushort hi = f2bf(xs[e]);
                bh[e] = (short)hi;
                bl[e] = (short)f2bf(xs[e] - bf2f(hi));
            }
            acc = __builtin_amdgcn_mfma_f32_16x16x32_bf16(qh[ks], bh, acc, 0, 0, 0);
            acc = __builtin_amdgcn_mfma_f32_16x16x32_bf16(ql[ks], bh, acc, 0, 0, 0);
            acc = __builtin_amdgcn_mfma_f32_16x16x32_bf16(qh[ks], bl, acc, 0, 0, 0);
        }
        int pcol = p0 + lm;
        if (pcol < NP) {
            #pragma unroll
            for (int e = 0; e < 4; ++e)
                sR[(4 * lg + e) * NP + pcol] = acc[e];
        }
    }
    __syncthreads();

    #pragma unroll
    for (int ks = 0; ks < 2; ++ks) {
        int ch = lg + 4 * ks;
        int ad = lm * 64 + ((ch ^ (lm & 7)) << 3);
        qh[ks] = *(const bf16x8*)&sQh[ad];
        ql[ks] = *(const bf16x8*)&sQl[ad];
    }
    f32x4 acc[4];
    #pragma unroll
    for (int t = 0; t < 4; ++t) {
        int j = (4 * w + t) * 16 + lm;
        const float* bsrc = Kbh + (size_t)j * DH + 8 * lg;
        acc[t] = (f32x4){0.f, 0.f, 0.f, 0.f};
        #pragma unroll
        for (int ks = 0; ks < 2; ++ks) {
            float4 v0 = *(const float4*)(bsrc + ks * 32);
            float4 v1 = *(const float4*)(bsrc + ks * 32 + 4);
            float xs[8] = {v0.x, v0.y, v0.z, v0.w, v1.x, v1.y, v1.z, v1.w};
            bf16x8 bh, bl;
            #pragma unroll
            for (int e = 0; e < 8; ++e) {
                ushort hi = f2bf(xs[e]);
                bh[e] = (short)hi;
                bl[e] = (short)f2bf(xs[e] - bf2f(hi));
            }
            acc[t] = __builtin_amdgcn_mfma_f32_16x16x32_bf16(qh[ks], bh, acc[t], 0, 0, 0);
            acc[t] = __builtin_amdgcn_mfma_f32_16x16x32_bf16(ql[ks], bh, acc[t], 0, 0, 0);
            acc[t] = __builtin_amdgcn_mfma_f32_16x16x32_bf16(qh[ks], bl, acc[t], 0, 0, 0);
        }
    }

    #pragma unroll
    for (int t = 0; t < 4; ++t) {
        int col = (4 * w + t) * 16 + lm;
        #pragma unroll
        for (int e = 0; e < 4; ++e) {
            int row = 4 * lg + e;
            size_t off = (size_t)(i0 + row) * LSEQ + col;
            int pm = PMb[off];
            int mk = MKb[off];
            float g = sR[row * NP + pm];
            acc[t][e] = (mk == 0) ? -1e9f : (acc[t][e] + g) * 0.125f;
        }
    }
    __syncthreads();
    for (int idxx = tid; idxx < TI * NP; idxx += 1024) sR[idxx] = 0.f;
    __syncthreads();

    float Mr[4];
    #pragma unroll
    for (int e = 0; e < 4; ++e) {
        float m = fmaxf(fmaxf(acc[0][e], acc[1][e]), fmaxf(acc[2][e], acc[3][e]));
        #pragma unroll
        for (int o = 8; o >= 1; o >>= 1) m = fmaxf(m, __shfl_xor(m, o));
        Mr[e] = m;
    }
    if (lm == 0) {
        #pragma unroll
        for (int e = 0; e < 4; ++e) sRed[(4 * lg + e) * 17 + w] = Mr[e];
    }
    __syncthreads();
    if (w == 0 && l < 16) {
        float m = -INFINITY;
        for (int ww = 0; ww < 16; ++ww) m = fmaxf(m, sRed[l * 17 + ww]);
        sFin[l] = m;
    }
    __syncthreads();
    #pragma unroll
    for (int e = 0; e < 4; ++e) Mr[e] = sFin[4 * lg + e];

    float Sr[4];
    #pragma unroll
    for (int e = 0; e < 4; ++e) {
        float s = 0.f;
        #pragma unroll
        for (int t = 0; t < 4; ++t) {
            float v = __expf(acc[t][e] - Mr[e]);
            acc[t][e] = v;
            s += v;
        }
        #pragma unroll
        for (int o = 8; o >= 1; o >>= 1) s += __shfl_xor(s, o);
        Sr[e] = s;
    }
    if (lm == 0) {
        #pragma unroll
        for (int e = 0; e < 4; ++e) sRed[(4 * lg + e) * 17 + w] = Sr[e];
    }
    __syncthreads();
    if (w == 0 && l < 16) {
        float s = 0.f;
        for (int ww = 0; ww < 16; ++ww) s += sRed[l * 17 + ww];
        sFin[l] = s;
    }
    __syncthreads();

    float inv[4];
    #pragma unroll
    for (int e = 0; e < 4; ++e) inv[e] = 1.0f / sFin[4 * lg + e];

    const size_t pbase = (((size_t)b * NH + h) * LSEQ + i0) * LSEQ;
    #pragma unroll
    for (int t = 0; t < 4; ++t) {
        int col = (4 * w + t) * 16 + lm;
        #pragma unroll
        for (int e = 0; e < 4; ++e) {
            int row = 4 * lg + e;
            float p = acc[t][e] * inv[e];
            OUT_P[pbase + (size_t)row * LSEQ + col] = p;
            int ad = row * 1024 + (((col >> 3) ^ (row & 7)) << 3) + (col & 7);
            sPb[ad] = f2bf(p);
            int pm = PMb[(size_t)(i0 + row) * LSEQ + col];
            atomicAdd(&sR[row * NP + pm], p);
        }
    }
    __syncthreads();

    if (w < 8) {
        int ct = w >> 1, jh = w & 1;
        int d = ct * 16 + lm;
        f32x4 pa = {0.f, 0.f, 0.f, 0.f};
        for (int ks = 0; ks < 16; ++ks) {
            int j0 = jh * 512 + ks * 32;
            int ch = (j0 >> 3) + lg;
            bf16x8 a = *(const bf16x8*)&sPb[lm * 1024 + ((ch ^ (lm & 7)) << 3)];
            const float* vs = Vbh + (size_t)(j0 + 8 * lg) * DH + d;
            bf16x8 bb;
            #pragma unroll
            for (int e = 0; e < 8; ++e) bb[e] = (short)f2bf(vs[(size_t)e * DH]);
            pa = __builtin_amdgcn_mfma_f32_16x16x32_bf16(a, bb, pa, 0, 0, 0);
        }
        #pragma unroll
        for (int e = 0; e < 4; ++e)
            atomicAdd(&sAttn[(4 * lg + e) * 64 + d], pa[e]);
    } else {
        int ct = (w - 8) >> 1, ph = w & 1;
        int d = ct * 16 + lm;
        int nks = ph ? 9 : 8;
        f32x4 pa = {0.f, 0.f, 0.f, 0.f};
        for (int ks = 0; ks < nks; ++ks) {
            int p0 = ph * 256 + ks * 32 + 8 * lg;
            bf16x8 a, bb;
            #pragma unroll
            for (int e = 0; e < 8; ++e) {
                int pp = p0 + e;
                float av = (pp < NP) ? sR[lm * NP + pp] : 0.f;
                a[e] = (short)f2bf(av);
                int pc = (pp < NP) ? pp : (NP - 1);
                bb[e] = (short)f2bf(RELb[(size_t)pc * DH + d]);
            }
            pa = __builtin_amdgcn_mfma_f32_16x16x32_bf16(a, bb, pa, 0, 0, 0);
        }
        #pragma unroll
        for (int e = 0; e < 4; ++e)
            atomicAdd(&sAttn[(4 * lg + e) * 64 + d], pa[e]);
    }
    __syncthreads();

    {
        int row = tid >> 6, col = tid & 63;
        OUT_A[(((size_t)b * NH + h) * LSEQ + i0 + row) * DH + col] =
            sAttn[row * 64 + col];
    }
}

extern "C" void kernel_launch(void* const* d_in, const int* in_sizes, int n_in,
                              void* d_out, int out_size, void* d_ws, size_t ws_size,
                              hipStream_t stream) {
    const float* q    = (const float*)d_in[0];
    const float* k    = (const float*)d_in[1];
    const float* v    = (const float*)d_in[2];
    const float* rel  = (const float*)d_in[3];
    const int*   pm   = (const int*)d_in[4];
    const int*   mask = (const int*)d_in[5];
    float* out_a = (float*)d_out;
    float* out_p = (float*)d_out + (size_t)BSZ * NH * LSEQ * DH;

    if (ws_size >= WS_NEED && d_ws != nullptr) {
        ushort* ws = (ushort*)d_ws;
        prep1<<<NB_P1, 256, 0, stream>>>(q, k, v, rel, ws);
        prep2<<<1024, 256, 0, stream>>>(pm, mask, ws);
        raa_qks<<<2048, 512, 0, stream>>>((const ushort*)ws, out_p);
        raa_pv<<<2048, 1024, 0, stream>>>((const ushort*)ws, out_p, out_a);
    } else {
        dim3 grid(LSEQ / TI, NH, BSZ);
        raa_fallback<<<grid, 1024, 0, stream>>>(q, k, v, rel, pm, mask, out_a, out_p);
    }
}